// Round 1
// baseline (1902.717 us; speedup 1.0000x reference)
//
#include <hip/hip_runtime.h>
#include <hip/hip_bf16.h>

#define NB 8192
#define TSTEPS 48

typedef __hip_bfloat16 bf16;
typedef short bf16x8 __attribute__((ext_vector_type(8)));
typedef float f32x4 __attribute__((ext_vector_type(4)));

__device__ __forceinline__ float sigf(float x) { return 1.0f / (1.0f + __expf(-x)); }
__device__ __forceinline__ float tanhf_fast(float x) { return 2.0f / (1.0f + __expf(-2.0f * x)) - 1.0f; }

// ---------------- feats precompute: [T, N, 32] bf16, upper 16 cols zero ----------------
__global__ void feats_kernel(const float* __restrict__ x, const float* __restrict__ coords,
                             const float* __restrict__ env, const float* __restrict__ areas,
                             const float* __restrict__ bird, bf16* __restrict__ feats) {
  int idx = blockIdx.x * 256 + threadIdx.x;  // = t*NB + n
  int n = idx & (NB - 1);
  int t = idx >> 13;
  __align__(16) bf16 v[32];
  v[0] = __float2bfloat16(x[n * TSTEPS + t]);
  v[1] = __float2bfloat16(coords[n * 2 + 0]);
  v[2] = __float2bfloat16(coords[n * 2 + 1]);
#pragma unroll
  for (int e = 0; e < 10; ++e) v[3 + e] = __float2bfloat16(env[(n * 10 + e) * TSTEPS + t]);
  v[13] = __float2bfloat16(areas[n]);
  v[14] = __float2bfloat16(bird[(n * 2 + 0) * TSTEPS + t]);
  v[15] = __float2bfloat16(bird[(n * 2 + 1) * TSTEPS + t]);
#pragma unroll
  for (int f = 16; f < 32; ++f) v[f] = __float2bfloat16(0.0f);
  bf16* dst = feats + (size_t)idx * 32;
#pragma unroll
  for (int c = 0; c < 4; ++c) ((bf16x8*)dst)[c] = ((const bf16x8*)v)[c];
}

// ---------------- weight packing ----------------
// packed gate-column order: j' = 128*q + 32*g + s  <->  original row j = 256*g + 32*q + s
__device__ __forceinline__ int orig_row(int jp) {
  int q = jp >> 7, g = (jp >> 5) & 3, s = jp & 31;
  return g * 256 + q * 32 + s;
}

// WA: [1024, 288] = [W_hh0 (256) | Wc0 = W_ih0@W_in (16) | zeros (16)]
__global__ void packA_kernel(const float* __restrict__ W_hh0, const float* __restrict__ W_ih0,
                             const float* __restrict__ W_in, bf16* __restrict__ WA) {
  int idx = blockIdx.x * 256 + threadIdx.x;  // < 1024*288
  int jp = idx / 288, col = idx % 288;
  int j = orig_row(jp);
  float val = 0.0f;
  if (col < 256) {
    val = W_hh0[j * 256 + col];
  } else if (col < 272) {
    int f = col - 256;
    float s = 0.0f;
    for (int k = 0; k < 256; ++k) s += W_ih0[j * 256 + k] * W_in[k * 16 + f];
    val = s;
  }
  WA[(size_t)jp * 288 + col] = __float2bfloat16(val);
}

// WB: [1024, 512] = [W_ih1 (256) | W_hh1 (256)]
__global__ void packB_kernel(const float* __restrict__ W_ih1, const float* __restrict__ W_hh1,
                             bf16* __restrict__ WB) {
  int idx = blockIdx.x * 256 + threadIdx.x;  // < 1024*512
  int jp = idx >> 9, col = idx & 511;
  int j = orig_row(jp);
  float val = (col < 256) ? W_ih1[j * 256 + col] : W_hh1[j * 256 + (col - 256)];
  WB[(size_t)jp * 512 + col] = __float2bfloat16(val);
}

__global__ void packBias_kernel(const float* __restrict__ b_ih, const float* __restrict__ b_hh,
                                float* __restrict__ bA, float* __restrict__ bB) {
  int idx = blockIdx.x * 256 + threadIdx.x;  // < 2048
  int layer = idx >> 10, jp = idx & 1023;
  int j = orig_row(jp);
  float v = b_ih[layer * 1024 + j] + b_hh[layer * 1024 + j];
  if (layer == 0) bA[jp] = v; else bB[jp] = v;
}

// ---------------- fused GEMM + LSTM cell step ----------------
// C[n, j'] = sum_k A[n,k] * Wp[j',k]; 128x128 tile, 4 waves, 16x16x32 bf16 MFMA.
// PHASE 0: A = S[:,0:256] (h0) for kb<8, feats[t] for kb==8 (KW=288).
// PHASE 1: A = S[:,0:512] ([h0|h1]), KW=512, 16 iters.
template <int KITERS, int KW, int PHASE>
__global__ __launch_bounds__(256, 2) void lstm_step(
    const bf16* __restrict__ S, const bf16* __restrict__ feats,
    const bf16* __restrict__ Wp, const float* __restrict__ bias,
    float* __restrict__ cst, bf16* __restrict__ hout,
    float* __restrict__ out_h, float* __restrict__ out_c, int t, int last) {
  __shared__ float Gs[64 * 132];
  bf16* As = (bf16*)Gs;        // [128][32]
  bf16* Bs = As + 128 * 32;    // [128][32]

  const int tid = threadIdx.x;
  const int wid = tid >> 6, lane = tid & 63;
  const int quad = lane >> 4, l16 = lane & 15;
  const int mb = (wid >> 1) * 64, nb = (wid & 1) * 64;
  const int rowbase = blockIdx.x * 128;
  const int q = blockIdx.y;

  f32x4 acc[4][4];
#pragma unroll
  for (int i = 0; i < 4; ++i)
#pragma unroll
    for (int j = 0; j < 4; ++j) acc[i][j] = f32x4{0.f, 0.f, 0.f, 0.f};

  const int srow = tid >> 2;   // 0..63
  const int schunk = tid & 3;  // 16B chunk within 32-col row

  for (int kb = 0; kb < KITERS; ++kb) {
    const bf16* Ag;
    int astride;
    if (PHASE == 0 && kb == KITERS - 1) {
      Ag = feats + ((size_t)t * NB + rowbase) * 32;
      astride = 32;
    } else {
      Ag = S + (size_t)rowbase * 512 + kb * 32;
      astride = 512;
    }
    const bf16* Bg = Wp + (size_t)(q * 128) * KW + kb * 32;
#pragma unroll
    for (int p = 0; p < 2; ++p) {
      int r = srow + p * 64;
      *(bf16x8*)&As[r * 32 + schunk * 8] = *(const bf16x8*)&Ag[(size_t)r * astride + schunk * 8];
      *(bf16x8*)&Bs[r * 32 + schunk * 8] = *(const bf16x8*)&Bg[(size_t)r * KW + schunk * 8];
    }
    __syncthreads();
    bf16x8 af[4], bfr[4];
#pragma unroll
    for (int i = 0; i < 4; ++i) af[i] = *(const bf16x8*)&As[(mb + i * 16 + l16) * 32 + quad * 8];
#pragma unroll
    for (int j = 0; j < 4; ++j) bfr[j] = *(const bf16x8*)&Bs[(nb + j * 16 + l16) * 32 + quad * 8];
#pragma unroll
    for (int i = 0; i < 4; ++i)
#pragma unroll
      for (int j = 0; j < 4; ++j)
        acc[i][j] = __builtin_amdgcn_mfma_f32_16x16x32_bf16(af[i], bfr[j], acc[i][j], 0, 0, 0);
    __syncthreads();
  }

  // epilogue: half-block at a time through LDS (keeps static LDS < 64KB)
  const int s = tid & 31;
  const int rg = tid >> 5;  // 0..7
  const float bi = bias[q * 128 + 0 + s];
  const float bf_ = bias[q * 128 + 32 + s];
  const float bg = bias[q * 128 + 64 + s];
  const float bo = bias[q * 128 + 96 + s];
  const int u = q * 32 + s;

  for (int half = 0; half < 2; ++half) {
    if ((wid >> 1) == half) {
#pragma unroll
      for (int i = 0; i < 4; ++i)
#pragma unroll
        for (int j = 0; j < 4; ++j)
#pragma unroll
          for (int r = 0; r < 4; ++r)
            Gs[(i * 16 + quad * 4 + r) * 132 + nb + j * 16 + l16] = acc[i][j][r];
    }
    __syncthreads();
#pragma unroll
    for (int it = 0; it < 8; ++it) {
      int rl = rg * 8 + it;  // 0..63
      int n = rowbase + half * 64 + rl;
      float gi = sigf(Gs[rl * 132 + 0 + s] + bi);
      float gf = sigf(Gs[rl * 132 + 32 + s] + bf_);
      float gg = tanhf_fast(Gs[rl * 132 + 64 + s] + bg);
      float go = sigf(Gs[rl * 132 + 96 + s] + bo);
      size_t ci = (size_t)n * 256 + u;
      float c = cst[ci];
      float cn = gf * c + gi * gg;
      float hn = go * tanhf_fast(cn);
      cst[ci] = cn;
      hout[(size_t)n * 512 + u] = __float2bfloat16(hn);
      if (last) {
        out_h[ci] = hn;
        out_c[ci] = cn;
      }
    }
    __syncthreads();
  }
}

extern "C" void kernel_launch(void* const* d_in, const int* in_sizes, int n_in,
                              void* d_out, int out_size, void* d_ws, size_t ws_size,
                              hipStream_t stream) {
  const float* x = (const float*)d_in[0];
  const float* coords = (const float*)d_in[1];
  const float* env = (const float*)d_in[2];
  const float* areas = (const float*)d_in[3];
  const float* bird = (const float*)d_in[4];
  const float* W_in = (const float*)d_in[5];
  const float* W_ih = (const float*)d_in[6];  // [2,1024,256]
  const float* W_hh = (const float*)d_in[7];  // [2,1024,256]
  const float* b_ih = (const float*)d_in[8];  // [2,1024]
  const float* b_hh = (const float*)d_in[9];  // [2,1024]
  float* out = (float*)d_out;

  char* w = (char*)d_ws;
  bf16* S = (bf16*)w;            w += (size_t)NB * 512 * 2;        // [N,512]: h0|h1
  float* c0 = (float*)w;         w += (size_t)NB * 256 * 4;
  float* c1 = (float*)w;         w += (size_t)NB * 256 * 4;
  bf16* feats = (bf16*)w;        w += (size_t)TSTEPS * NB * 32 * 2;
  bf16* WA = (bf16*)w;           w += (size_t)1024 * 288 * 2;
  bf16* WB = (bf16*)w;           w += (size_t)1024 * 512 * 2;
  float* bA = (float*)w;         w += 1024 * 4;
  float* bB = (float*)w;         w += 1024 * 4;

  // zero h-state and c-state (ws is poisoned before every launch)
  hipMemsetAsync(d_ws, 0, (size_t)NB * 512 * 2 + 2 * (size_t)NB * 256 * 4, stream);

  feats_kernel<<<(NB * TSTEPS) / 256, 256, 0, stream>>>(x, coords, env, areas, bird, feats);
  packA_kernel<<<(1024 * 288) / 256, 256, 0, stream>>>(W_hh, W_ih, W_in, WA);
  packB_kernel<<<(1024 * 512) / 256, 256, 0, stream>>>(W_ih + 1024 * 256, W_hh + 1024 * 256, WB);
  packBias_kernel<<<2048 / 256, 256, 0, stream>>>(b_ih, b_hh, bA, bB);

  dim3 grid(NB / 128, 8);
  const size_t NH = (size_t)NB * 256;
  for (int tt = 0; tt < TSTEPS; ++tt) {
    int last = (tt == TSTEPS - 1);
    lstm_step<9, 288, 0><<<grid, 256, 0, stream>>>(
        S, feats, WA, bA, c0, S, out + 0 * NH, out + 2 * NH, tt, last);
    lstm_step<16, 512, 1><<<grid, 256, 0, stream>>>(
        S, nullptr, WB, bB, c1, S + 256, out + 1 * NH, out + 3 * NH, tt, last);
  }
}

// Round 2
// 1553.132 us; speedup vs baseline: 1.2251x; 1.2251x over previous
//
#include <hip/hip_runtime.h>
#include <hip/hip_bf16.h>
#include <cstdint>

#define NB 8192
#define TSTEPS 48

typedef __hip_bfloat16 bf16;
typedef short bf16x8 __attribute__((ext_vector_type(8)));
typedef float f32x4 __attribute__((ext_vector_type(4)));

__device__ __forceinline__ float sigf(float x) { return 1.0f / (1.0f + __expf(-x)); }
__device__ __forceinline__ float tanhf_fast(float x) { return 2.0f / (1.0f + __expf(-2.0f * x)) - 1.0f; }

// CK-style async global->LDS, 16B per lane. LDS dest = wave-uniform base + lane*16.
__device__ __forceinline__ void gld_lds16(const void* g, void* l) {
  typedef const __attribute__((address_space(1))) unsigned int* gp_t;
  typedef __attribute__((address_space(3))) unsigned int* lp_t;
  __builtin_amdgcn_global_load_lds(reinterpret_cast<gp_t>(reinterpret_cast<uintptr_t>(g)),
                                   reinterpret_cast<lp_t>(reinterpret_cast<uintptr_t>(l)),
                                   16, 0, 0);
}

// ---------------- feats precompute: [T, N, 32] bf16, upper 16 cols zero ----------------
__global__ void feats_kernel(const float* __restrict__ x, const float* __restrict__ coords,
                             const float* __restrict__ env, const float* __restrict__ areas,
                             const float* __restrict__ bird, bf16* __restrict__ feats) {
  int idx = blockIdx.x * 256 + threadIdx.x;  // = t*NB + n
  int n = idx & (NB - 1);
  int t = idx >> 13;
  __align__(16) bf16 v[32];
  v[0] = __float2bfloat16(x[n * TSTEPS + t]);
  v[1] = __float2bfloat16(coords[n * 2 + 0]);
  v[2] = __float2bfloat16(coords[n * 2 + 1]);
#pragma unroll
  for (int e = 0; e < 10; ++e) v[3 + e] = __float2bfloat16(env[(n * 10 + e) * TSTEPS + t]);
  v[13] = __float2bfloat16(areas[n]);
  v[14] = __float2bfloat16(bird[(n * 2 + 0) * TSTEPS + t]);
  v[15] = __float2bfloat16(bird[(n * 2 + 1) * TSTEPS + t]);
#pragma unroll
  for (int f = 16; f < 32; ++f) v[f] = __float2bfloat16(0.0f);
  bf16* dst = feats + (size_t)idx * 32;
#pragma unroll
  for (int c = 0; c < 4; ++c) ((bf16x8*)dst)[c] = ((const bf16x8*)v)[c];
}

// ---------------- weight packing ----------------
// packed gate-column order: j' = 128*q + 32*g + s  <->  original row j = 256*g + 32*q + s
__device__ __forceinline__ int orig_row(int jp) {
  int q = jp >> 7, g = (jp >> 5) & 3, s = jp & 31;
  return g * 256 + q * 32 + s;
}

// WA: [1024, 288] = [W_hh0 (256) | Wc0 = W_ih0@W_in (16) | zeros (16)]
__global__ void packA_kernel(const float* __restrict__ W_hh0, const float* __restrict__ W_ih0,
                             const float* __restrict__ W_in, bf16* __restrict__ WA) {
  int idx = blockIdx.x * 256 + threadIdx.x;  // < 1024*288
  int jp = idx / 288, col = idx % 288;
  int j = orig_row(jp);
  float val = 0.0f;
  if (col < 256) {
    val = W_hh0[j * 256 + col];
  } else if (col < 272) {
    int f = col - 256;
    float s = 0.0f;
    for (int k = 0; k < 256; ++k) s += W_ih0[j * 256 + k] * W_in[k * 16 + f];
    val = s;
  }
  WA[(size_t)jp * 288 + col] = __float2bfloat16(val);
}

// WB: [1024, 512] = [W_ih1 (256) | W_hh1 (256)]
__global__ void packB_kernel(const float* __restrict__ W_ih1, const float* __restrict__ W_hh1,
                             bf16* __restrict__ WB) {
  int idx = blockIdx.x * 256 + threadIdx.x;  // < 1024*512
  int jp = idx >> 9, col = idx & 511;
  int j = orig_row(jp);
  float val = (col < 256) ? W_ih1[j * 256 + col] : W_hh1[j * 256 + (col - 256)];
  WB[(size_t)jp * 512 + col] = __float2bfloat16(val);
}

__global__ void packBias_kernel(const float* __restrict__ b_ih, const float* __restrict__ b_hh,
                                float* __restrict__ bA, float* __restrict__ bB) {
  int idx = blockIdx.x * 256 + threadIdx.x;  // < 2048
  int layer = idx >> 10, jp = idx & 1023;
  int j = orig_row(jp);
  float v = b_ih[layer * 1024 + j] + b_hh[layer * 1024 + j];
  if (layer == 0) bA[jp] = v; else bB[jp] = v;
}

// ---------------- fused GEMM + LSTM cell step, combined A/B phases ----------------
// phase = blockIdx.z + phase0:  0 = layer-1 at tB (B), 1 = layer-0 at tA (A).
// A: C = h0r[8192,256] @ WA cols 0..255 + feats(tA) @ WA cols 256..287 (pad to 288)
// B: C = h0r @ WB cols 0..255 + h1r @ WB cols 256..511
// All state buffers [8192,256] bf16 row-major; double-buffered across time (no races).
__global__ __launch_bounds__(256, 2) void lstm_step(
    const bf16* __restrict__ h0r, bf16* __restrict__ h0w,
    const bf16* __restrict__ h1r, bf16* __restrict__ h1w,
    const bf16* __restrict__ feats,
    const bf16* __restrict__ WA, const bf16* __restrict__ WB,
    const float* __restrict__ bA, const float* __restrict__ bB,
    float* __restrict__ c0, float* __restrict__ c1,
    float* __restrict__ out, int tA, int tB, int phase0, int lastA, int lastB) {
  __shared__ float Gs[64 * 132];
  bf16* As = (bf16*)Gs;        // [128][32]
  bf16* Bs = As + 128 * 32;    // [128][32]

  const int tid = threadIdx.x;
  const int wid = tid >> 6, lane = tid & 63;
  const int quad = lane >> 4, l16 = lane & 15;
  const int mb = (wid >> 1) * 64, nb = (wid & 1) * 64;
  const int rowbase = blockIdx.x * 128;
  const int q = blockIdx.y;
  const int isA = blockIdx.z + phase0;  // 0 = B, 1 = A

  const bf16* Wp = isA ? WA : WB;
  const int KW = isA ? 288 : 512;
  const int KITERS = isA ? 9 : 16;
  const float* bias = isA ? bA : bB;
  float* cst = isA ? c0 : c1;
  bf16* hout = isA ? h0w : h1w;
  const int t = isA ? tA : tB;
  const int last = isA ? lastA : lastB;
  float* out_h = out + (size_t)(isA ? 0 : 1) * NB * 256;
  float* out_c = out + (size_t)(isA ? 2 : 3) * NB * 256;

  f32x4 acc[4][4];
#pragma unroll
  for (int i = 0; i < 4; ++i)
#pragma unroll
    for (int j = 0; j < 4; ++j) acc[i][j] = f32x4{0.f, 0.f, 0.f, 0.f};

  const int arow = wid * 32 + (lane >> 2);  // staging row within 128-tile (this wave: 2x16 rows)
  const int achunk = (lane & 3) * 8;        // element offset within 32-col row
  bf16* lA = As + wid * 32 * 32;            // wave-uniform LDS bases
  bf16* lB = Bs + wid * 32 * 32;
  const bf16* WGrow = Wp + (size_t)(q * 128 + arow) * KW + achunk;

  for (int kb = 0; kb < KITERS; ++kb) {
    const bf16* Arow;
    int astr;
    if (isA && kb == 8) {
      Arow = feats + ((size_t)t * NB + rowbase) * 32;
      astr = 32;
    } else {
      const bf16* src = (!isA && kb >= 8) ? (h1r + (kb - 8) * 32) : (h0r + kb * 32);
      Arow = src + (size_t)rowbase * 256;
      astr = 256;
    }
    const bf16* ga = Arow + (size_t)arow * astr + achunk;
    const bf16* gb = WGrow + kb * 32;
    gld_lds16(ga, lA);
    gld_lds16(ga + (size_t)16 * astr, lA + 16 * 32);
    gld_lds16(gb, lB);
    gld_lds16(gb + (size_t)16 * KW, lB + 16 * 32);
    __syncthreads();  // compiler emits vmcnt(0) drain before barrier -> LDS visible
    bf16x8 af[4], bfr[4];
#pragma unroll
    for (int i = 0; i < 4; ++i) af[i] = *(const bf16x8*)&As[(mb + i * 16 + l16) * 32 + quad * 8];
#pragma unroll
    for (int j = 0; j < 4; ++j) bfr[j] = *(const bf16x8*)&Bs[(nb + j * 16 + l16) * 32 + quad * 8];
#pragma unroll
    for (int i = 0; i < 4; ++i)
#pragma unroll
      for (int j = 0; j < 4; ++j)
        acc[i][j] = __builtin_amdgcn_mfma_f32_16x16x32_bf16(af[i], bfr[j], acc[i][j], 0, 0, 0);
    __syncthreads();
  }

  // epilogue: half-block at a time through LDS (aliases As/Bs; all waves past final barrier)
  const int s = tid & 31;
  const int rg = tid >> 5;  // 0..7
  const float bi = bias[q * 128 + 0 + s];
  const float bf_ = bias[q * 128 + 32 + s];
  const float bg = bias[q * 128 + 64 + s];
  const float bo = bias[q * 128 + 96 + s];
  const int u = q * 32 + s;

  for (int half = 0; half < 2; ++half) {
    if ((wid >> 1) == half) {
#pragma unroll
      for (int i = 0; i < 4; ++i)
#pragma unroll
        for (int j = 0; j < 4; ++j)
#pragma unroll
          for (int r = 0; r < 4; ++r)
            Gs[(i * 16 + quad * 4 + r) * 132 + nb + j * 16 + l16] = acc[i][j][r];
    }
    __syncthreads();
#pragma unroll
    for (int it = 0; it < 8; ++it) {
      int rl = rg * 8 + it;  // 0..63
      int n = rowbase + half * 64 + rl;
      float gi = sigf(Gs[rl * 132 + 0 + s] + bi);
      float gf = sigf(Gs[rl * 132 + 32 + s] + bf_);
      float gg = tanhf_fast(Gs[rl * 132 + 64 + s] + bg);
      float go = sigf(Gs[rl * 132 + 96 + s] + bo);
      size_t ci = (size_t)n * 256 + u;
      float c = cst[ci];
      float cn = gf * c + gi * gg;
      float hn = go * tanhf_fast(cn);
      cst[ci] = cn;
      hout[ci] = __float2bfloat16(hn);
      if (last) {
        out_h[ci] = hn;
        out_c[ci] = cn;
      }
    }
    __syncthreads();
  }
}

extern "C" void kernel_launch(void* const* d_in, const int* in_sizes, int n_in,
                              void* d_out, int out_size, void* d_ws, size_t ws_size,
                              hipStream_t stream) {
  const float* x = (const float*)d_in[0];
  const float* coords = (const float*)d_in[1];
  const float* env = (const float*)d_in[2];
  const float* areas = (const float*)d_in[3];
  const float* bird = (const float*)d_in[4];
  const float* W_in = (const float*)d_in[5];
  const float* W_ih = (const float*)d_in[6];  // [2,1024,256]
  const float* W_hh = (const float*)d_in[7];  // [2,1024,256]
  const float* b_ih = (const float*)d_in[8];  // [2,1024]
  const float* b_hh = (const float*)d_in[9];  // [2,1024]
  float* out = (float*)d_out;

  const size_t MB = 1 << 20;
  char* w0 = (char*)d_ws;
  // layout: [H0_0 4MB][H1_0 4MB][H0_1 4MB][H1_1 4MB][c0 8MB][c1 8MB][feats 24MB][WA][WB][bA][bB]
  auto H0 = [&](int i) { return (bf16*)(w0 + (size_t)i * 8 * MB); };
  auto H1 = [&](int i) { return (bf16*)(w0 + 4 * MB + (size_t)i * 8 * MB); };
  float* c0 = (float*)(w0 + 16 * MB);
  float* c1 = (float*)(w0 + 24 * MB);
  bf16* feats = (bf16*)(w0 + 32 * MB);
  bf16* WA = (bf16*)(w0 + 56 * MB);
  bf16* WB = (bf16*)(w0 + 57 * MB);
  float* bA = (float*)(w0 + 58 * MB);
  float* bB = (float*)(w0 + 58 * MB + 4096);

  // zero H0[1], H1[1] (initial state) and c0, c1 — contiguous [8MB, 32MB)
  hipMemsetAsync(w0 + 8 * MB, 0, 24 * MB, stream);

  feats_kernel<<<(NB * TSTEPS) / 256, 256, 0, stream>>>(x, coords, env, areas, bird, feats);
  packA_kernel<<<(1024 * 288) / 256, 256, 0, stream>>>(W_hh, W_ih, W_in, WA);
  packB_kernel<<<(1024 * 512) / 256, 256, 0, stream>>>(W_ih + 1024 * 256, W_hh + 1024 * 256, WB);
  packBias_kernel<<<2048 / 256, 256, 0, stream>>>(b_ih, b_hh, bA, bB);

  // A(0): reads H0[1] (zero), writes H0[0]
  lstm_step<<<dim3(64, 8, 1), 256, 0, stream>>>(
      H0(1), H0(0), H1(0), H1(1), feats, WA, WB, bA, bB, c0, c1, out,
      /*tA*/0, /*tB*/0, /*phase0*/1, /*lastA*/0, /*lastB*/0);
  // combined: z=0 -> B(s), z=1 -> A(s+1). Both read h0(s)=H0[s&1].
  for (int s2 = 0; s2 <= 46; ++s2) {
    int pa = (s2 + 1) & 1, pb = s2 & 1;
    lstm_step<<<dim3(64, 8, 2), 256, 0, stream>>>(
        H0(pb), H0(pa), H1(pa), H1(pb), feats, WA, WB, bA, bB, c0, c1, out,
        /*tA*/s2 + 1, /*tB*/s2, /*phase0*/0, /*lastA*/(s2 == 46), /*lastB*/0);
  }
  // B(47): reads H0[1], H1[0]; writes H1[1]
  lstm_step<<<dim3(64, 8, 1), 256, 0, stream>>>(
      H0(1), H0(0), H1(0), H1(1), feats, WA, WB, bA, bB, c0, c1, out,
      /*tA*/0, /*tB*/47, /*phase0*/0, /*lastA*/0, /*lastB*/1);
}

// Round 4
// 1491.978 us; speedup vs baseline: 1.2753x; 1.0410x over previous
//
#include <hip/hip_runtime.h>
#include <hip/hip_bf16.h>
#include <cstdint>

#define NB 8192
#define TSTEPS 48

typedef __hip_bfloat16 bf16;
typedef short bf16x8 __attribute__((ext_vector_type(8)));
typedef float f32x4 __attribute__((ext_vector_type(4)));

__device__ __forceinline__ float sigf(float x) { return 1.0f / (1.0f + __expf(-x)); }
__device__ __forceinline__ float tanhf_fast(float x) { return 2.0f / (1.0f + __expf(-2.0f * x)) - 1.0f; }

// CK-style async global->LDS, 16B per lane. LDS dest = wave-uniform base + lane*16.
__device__ __forceinline__ void gld_lds16(const void* g, void* l) {
  typedef const __attribute__((address_space(1))) unsigned int* gp_t;
  typedef __attribute__((address_space(3))) unsigned int* lp_t;
  __builtin_amdgcn_global_load_lds(reinterpret_cast<gp_t>(reinterpret_cast<uintptr_t>(g)),
                                   reinterpret_cast<lp_t>(reinterpret_cast<uintptr_t>(l)),
                                   16, 0, 0);
}

// ---------------- feats precompute: [T, N, 32] bf16, upper 16 cols zero ----------------
__global__ void feats_kernel(const float* __restrict__ x, const float* __restrict__ coords,
                             const float* __restrict__ env, const float* __restrict__ areas,
                             const float* __restrict__ bird, bf16* __restrict__ feats) {
  int idx = blockIdx.x * 256 + threadIdx.x;  // = t*NB + n
  int n = idx & (NB - 1);
  int t = idx >> 13;
  __align__(16) bf16 v[32];
  v[0] = __float2bfloat16(x[n * TSTEPS + t]);
  v[1] = __float2bfloat16(coords[n * 2 + 0]);
  v[2] = __float2bfloat16(coords[n * 2 + 1]);
#pragma unroll
  for (int e = 0; e < 10; ++e) v[3 + e] = __float2bfloat16(env[(n * 10 + e) * TSTEPS + t]);
  v[13] = __float2bfloat16(areas[n]);
  v[14] = __float2bfloat16(bird[(n * 2 + 0) * TSTEPS + t]);
  v[15] = __float2bfloat16(bird[(n * 2 + 1) * TSTEPS + t]);
#pragma unroll
  for (int f = 16; f < 32; ++f) v[f] = __float2bfloat16(0.0f);
  bf16* dst = feats + (size_t)idx * 32;
#pragma unroll
  for (int c = 0; c < 4; ++c) ((bf16x8*)dst)[c] = ((const bf16x8*)v)[c];
}

// ---------------- weight packing ----------------
// packed gate-column order: j' = 128*q + 32*g + s  <->  original row j = 256*g + 32*q + s
__device__ __forceinline__ int orig_row(int jp) {
  int q = jp >> 7, g = (jp >> 5) & 3, s = jp & 31;
  return g * 256 + q * 32 + s;
}

// WA: [1024, 288] = [W_hh0 (256) | Wc0 = W_ih0@W_in (16) | zeros (16)]
__global__ void packA_kernel(const float* __restrict__ W_hh0, const float* __restrict__ W_ih0,
                             const float* __restrict__ W_in, bf16* __restrict__ WA) {
  int idx = blockIdx.x * 256 + threadIdx.x;  // < 1024*288
  int jp = idx / 288, col = idx % 288;
  int j = orig_row(jp);
  float val = 0.0f;
  if (col < 256) {
    val = W_hh0[j * 256 + col];
  } else if (col < 272) {
    int f = col - 256;
    float s = 0.0f;
    for (int k = 0; k < 256; ++k) s += W_ih0[j * 256 + k] * W_in[k * 16 + f];
    val = s;
  }
  WA[(size_t)jp * 288 + col] = __float2bfloat16(val);
}

// WB: [1024, 512] = [W_ih1 (256) | W_hh1 (256)]
__global__ void packB_kernel(const float* __restrict__ W_ih1, const float* __restrict__ W_hh1,
                             bf16* __restrict__ WB) {
  int idx = blockIdx.x * 256 + threadIdx.x;  // < 1024*512
  int jp = idx >> 9, col = idx & 511;
  int j = orig_row(jp);
  float val = (col < 256) ? W_ih1[j * 256 + col] : W_hh1[j * 256 + (col - 256)];
  WB[(size_t)jp * 512 + col] = __float2bfloat16(val);
}

__global__ void packBias_kernel(const float* __restrict__ b_ih, const float* __restrict__ b_hh,
                                float* __restrict__ bA, float* __restrict__ bB) {
  int idx = blockIdx.x * 256 + threadIdx.x;  // < 2048
  int layer = idx >> 10, jp = idx & 1023;
  int j = orig_row(jp);
  float v = b_ih[layer * 1024 + j] + b_hh[layer * 1024 + j];
  if (layer == 0) bA[jp] = v; else bB[jp] = v;
}

// ---------------- fused GEMM + LSTM cell step, combined A/B phases ----------------
// phase = blockIdx.z + phase0:  0 = layer-1 at tB (B), 1 = layer-0 at tA (A).
// A: C = h0r[8192,256] @ WA cols 0..255 + feats(tA) @ WA cols 256..287 (pad to 288)
// B: C = h0r @ WB cols 0..255 + h1r @ WB cols 256..511
// All state buffers [8192,256] bf16 row-major; double-buffered across time (no races).
// R4: identical memory structure to the verified R2 kernel; only change is
// __launch_bounds__(256,4) -> VGPR cap 128 -> 4 blocks/CU (LDS 33.8KB allows 4).
__global__ __launch_bounds__(256, 4) void lstm_step(
    const bf16* __restrict__ h0r, bf16* __restrict__ h0w,
    const bf16* __restrict__ h1r, bf16* __restrict__ h1w,
    const bf16* __restrict__ feats,
    const bf16* __restrict__ WA, const bf16* __restrict__ WB,
    const float* __restrict__ bA, const float* __restrict__ bB,
    float* __restrict__ c0, float* __restrict__ c1,
    float* __restrict__ out, int tA, int tB, int phase0, int lastA, int lastB) {
  __shared__ float Gs[64 * 132];
  bf16* As = (bf16*)Gs;        // [128][32]
  bf16* Bs = As + 128 * 32;    // [128][32]

  const int tid = threadIdx.x;
  const int wid = tid >> 6, lane = tid & 63;
  const int quad = lane >> 4, l16 = lane & 15;
  const int mb = (wid >> 1) * 64, nb = (wid & 1) * 64;
  const int rowbase = blockIdx.x * 128;
  const int q = blockIdx.y;
  const int isA = blockIdx.z + phase0;  // 0 = B, 1 = A

  const bf16* Wp = isA ? WA : WB;
  const int KW = isA ? 288 : 512;
  const int KITERS = isA ? 9 : 16;
  const int t = isA ? tA : tB;

  f32x4 acc[4][4];
#pragma unroll
  for (int i = 0; i < 4; ++i)
#pragma unroll
    for (int j = 0; j < 4; ++j) acc[i][j] = f32x4{0.f, 0.f, 0.f, 0.f};

  const int arow = wid * 32 + (lane >> 2);  // staging row within 128-tile
  const int achunk = (lane & 3) * 8;        // element offset within 32-col row
  const bf16* WGrow = Wp + (size_t)(q * 128 + arow) * KW + achunk;
  bf16* lA = As + wid * 1024;  // wave-uniform LDS bases (wave stages rows wid*32..wid*32+31)
  bf16* lB = Bs + wid * 1024;

  for (int kb = 0; kb < KITERS; ++kb) {
    const bf16* Arow;
    int astr;
    if (isA && kb == 8) {
      Arow = feats + ((size_t)t * NB + rowbase) * 32;
      astr = 32;
    } else {
      const bf16* src = (!isA && kb >= 8) ? (h1r + (kb - 8) * 32) : (h0r + kb * 32);
      Arow = src + (size_t)rowbase * 256;
      astr = 256;
    }
    const bf16* ga = Arow + (size_t)arow * astr + achunk;
    const bf16* gb = WGrow + kb * 32;
    gld_lds16(ga, lA);
    gld_lds16(ga + (size_t)16 * astr, lA + 512);
    gld_lds16(gb, lB);
    gld_lds16(gb + (size_t)16 * KW, lB + 512);
    __syncthreads();  // vmcnt drain publishes staged tiles (m97-verified structure)
    bf16x8 af[4], bfr[4];
#pragma unroll
    for (int i = 0; i < 4; ++i) af[i] = *(const bf16x8*)&As[(mb + i * 16 + l16) * 32 + quad * 8];
#pragma unroll
    for (int j = 0; j < 4; ++j) bfr[j] = *(const bf16x8*)&Bs[(nb + j * 16 + l16) * 32 + quad * 8];
#pragma unroll
    for (int i = 0; i < 4; ++i)
#pragma unroll
      for (int j = 0; j < 4; ++j)
        acc[i][j] = __builtin_amdgcn_mfma_f32_16x16x32_bf16(af[i], bfr[j], acc[i][j], 0, 0, 0);
    __syncthreads();  // retire reads before next iteration's staging writes
  }

  // epilogue: half-block at a time through LDS (aliases As/Bs; all waves past final barrier)
  const float* bias = isA ? bA : bB;
  float* cst = isA ? c0 : c1;
  bf16* hout = isA ? h0w : h1w;
  const int last = isA ? lastA : lastB;
  float* out_h = out + (size_t)(isA ? 0 : 1) * NB * 256;
  float* out_c = out + (size_t)(isA ? 2 : 3) * NB * 256;

  const int s = tid & 31;
  const int rg = tid >> 5;  // 0..7
  const float bi = bias[q * 128 + 0 + s];
  const float bf_ = bias[q * 128 + 32 + s];
  const float bg = bias[q * 128 + 64 + s];
  const float bo = bias[q * 128 + 96 + s];
  const int u = q * 32 + s;

  for (int half = 0; half < 2; ++half) {
    if ((wid >> 1) == half) {
#pragma unroll
      for (int i = 0; i < 4; ++i)
#pragma unroll
        for (int j = 0; j < 4; ++j)
#pragma unroll
          for (int r = 0; r < 4; ++r)
            Gs[(i * 16 + quad * 4 + r) * 132 + nb + j * 16 + l16] = acc[i][j][r];
    }
    __syncthreads();
#pragma unroll
    for (int it = 0; it < 8; ++it) {
      int rl = rg * 8 + it;  // 0..63
      int n = rowbase + half * 64 + rl;
      float gi = sigf(Gs[rl * 132 + 0 + s] + bi);
      float gf = sigf(Gs[rl * 132 + 32 + s] + bf_);
      float gg = tanhf_fast(Gs[rl * 132 + 64 + s] + bg);
      float go = sigf(Gs[rl * 132 + 96 + s] + bo);
      size_t ci = (size_t)n * 256 + u;
      float c = cst[ci];
      float cn = gf * c + gi * gg;
      float hn = go * tanhf_fast(cn);
      cst[ci] = cn;
      hout[ci] = __float2bfloat16(hn);
      if (last) {
        out_h[ci] = hn;
        out_c[ci] = cn;
      }
    }
    __syncthreads();
  }
}

extern "C" void kernel_launch(void* const* d_in, const int* in_sizes, int n_in,
                              void* d_out, int out_size, void* d_ws, size_t ws_size,
                              hipStream_t stream) {
  const float* x = (const float*)d_in[0];
  const float* coords = (const float*)d_in[1];
  const float* env = (const float*)d_in[2];
  const float* areas = (const float*)d_in[3];
  const float* bird = (const float*)d_in[4];
  const float* W_in = (const float*)d_in[5];
  const float* W_ih = (const float*)d_in[6];  // [2,1024,256]
  const float* W_hh = (const float*)d_in[7];  // [2,1024,256]
  const float* b_ih = (const float*)d_in[8];  // [2,1024]
  const float* b_hh = (const float*)d_in[9];  // [2,1024]
  float* out = (float*)d_out;

  const size_t MB = 1 << 20;
  char* w0 = (char*)d_ws;
  // layout: [H0_0 4MB][H1_0 4MB][H0_1 4MB][H1_1 4MB][c0 8MB][c1 8MB][feats 24MB][WA][WB][bA][bB]
  auto H0 = [&](int i) { return (bf16*)(w0 + (size_t)i * 8 * MB); };
  auto H1 = [&](int i) { return (bf16*)(w0 + 4 * MB + (size_t)i * 8 * MB); };
  float* c0 = (float*)(w0 + 16 * MB);
  float* c1 = (float*)(w0 + 24 * MB);
  bf16* feats = (bf16*)(w0 + 32 * MB);
  bf16* WA = (bf16*)(w0 + 56 * MB);
  bf16* WB = (bf16*)(w0 + 57 * MB);
  float* bA = (float*)(w0 + 58 * MB);
  float* bB = (float*)(w0 + 58 * MB + 4096);

  // zero H0[1], H1[1] (initial state) and c0, c1 — contiguous [8MB, 32MB)
  hipMemsetAsync(w0 + 8 * MB, 0, 24 * MB, stream);

  feats_kernel<<<(NB * TSTEPS) / 256, 256, 0, stream>>>(x, coords, env, areas, bird, feats);
  packA_kernel<<<(1024 * 288) / 256, 256, 0, stream>>>(W_hh, W_ih, W_in, WA);
  packB_kernel<<<(1024 * 512) / 256, 256, 0, stream>>>(W_ih + 1024 * 256, W_hh + 1024 * 256, WB);
  packBias_kernel<<<2048 / 256, 256, 0, stream>>>(b_ih, b_hh, bA, bB);

  // A(0): reads H0[1] (zero), writes H0[0]
  lstm_step<<<dim3(64, 8, 1), 256, 0, stream>>>(
      H0(1), H0(0), H1(0), H1(1), feats, WA, WB, bA, bB, c0, c1, out,
      /*tA*/0, /*tB*/0, /*phase0*/1, /*lastA*/0, /*lastB*/0);
  // combined: z=0 -> B(s), z=1 -> A(s+1). Both read h0(s)=H0[s&1].
  for (int s2 = 0; s2 <= 46; ++s2) {
    int pa = (s2 + 1) & 1, pb = s2 & 1;
    lstm_step<<<dim3(64, 8, 2), 256, 0, stream>>>(
        H0(pb), H0(pa), H1(pa), H1(pb), feats, WA, WB, bA, bB, c0, c1, out,
        /*tA*/s2 + 1, /*tB*/s2, /*phase0*/0, /*lastA*/(s2 == 46), /*lastB*/0);
  }
  // B(47): reads H0[1], H1[0]; writes H1[1]
  lstm_step<<<dim3(64, 8, 1), 256, 0, stream>>>(
      H0(1), H0(0), H1(0), H1(1), feats, WA, WB, bA, bB, c0, c1, out,
      /*tA*/0, /*tB*/47, /*phase0*/0, /*lastA*/0, /*lastB*/1);
}